// Round 5
// baseline (283.213 us; speedup 1.0000x reference)
//
#include <hip/hip_runtime.h>

#define EPSF 1e-6f
#define DD 2048
#define SS 1024
#define BB 2
#define HH 16

typedef float fx4 __attribute__((ext_vector_type(4)));

// ws float layout: [0,2048) wsum (column sums of Wd); [2048] sum(bd)

__global__ __launch_bounds__(256) void k_colsum(const float* __restrict__ Wd,
                                                const float* __restrict__ bd,
                                                float* __restrict__ ws) {
    // 256 blocks: dchunk = bid & 7 (8 x 256 columns), echunk = bid >> 3 (32 x 64 rows)
    int dchunk = blockIdx.x & 7;
    int echunk = blockIdx.x >> 3;
    int d = dchunk * 256 + threadIdx.x;
    const float* p = Wd + (size_t)(echunk * 64) * DD + d;
    float acc = 0.f;
#pragma unroll 8
    for (int e = 0; e < 64; ++e) acc += p[(size_t)e * DD];
    atomicAdd(ws + d, acc);
    if (echunk == 0) {  // block-uniform: 8 blocks also reduce bd -> ws[2048]
        float accb = bd[d];
#pragma unroll
        for (int off = 32; off > 0; off >>= 1) accb += __shfl_down(accb, off);
        __shared__ float rb[4];
        if ((threadIdx.x & 63) == 0) rb[threadIdx.x >> 6] = accb;
        __syncthreads();
        if (threadIdx.x == 0) atomicAdd(ws + DD, rb[0] + rb[1] + rb[2] + rb[3]);
    }
}

__global__ __launch_bounds__(256) void k_norm(const float* __restrict__ aw,
                                              const float* __restrict__ x,
                                              const float* __restrict__ ws,
                                              const float* __restrict__ gW,
                                              const float* __restrict__ gb,
                                              float* __restrict__ out) {
    // 8192 blocks; each block = one (b,s) x 4 heads (one head-row per wave).
    // One shared gate value per block, computed from dot(x[b,s,:], wsum).
    int t = threadIdx.x;
    int w = t >> 6, lane = t & 63;
    int bid = blockIdx.x;
    int s = bid & (SS - 1);
    int hg = (bid >> 10) & 3;
    int b = bid >> 12;
    int h = hg * 4 + w;
    size_t rowbase = ((size_t)((b * HH + h) * SS + s)) * SS;
    const fx4* r = (const fx4*)(aw + rowbase);
    fx4 v[4];
#pragma unroll
    for (int k = 0; k < 4; ++k)
        v[k] = __builtin_nontemporal_load(r + lane + k * 64);

    // block-shared gate: he = (dot(x_row, wsum) + sum(bd)) / D
    const fx4* xr = (const fx4*)(x + ((size_t)(b * SS + s)) * DD);
    const fx4* wr = (const fx4*)ws;
    float accd = 0.f;
#pragma unroll
    for (int k = 0; k < 2; ++k) {
        fx4 xv = xr[t + k * 256];
        fx4 wv = wr[t + k * 256];
        accd += xv.x * wv.x + xv.y * wv.y + xv.z * wv.z + xv.w * wv.w;
    }
#pragma unroll
    for (int off = 32; off > 0; off >>= 1) accd += __shfl_down(accd, off);
    __shared__ float redd[4];
    if (lane == 0) redd[w] = accd;
    __syncthreads();
    float he = (redd[0] + redd[1] + redd[2] + redd[3] + ws[DD]) * (1.f / DD);
    // G = 1/((he+EPS) - 0.1i): Re = a/(a^2+0.01), Im = 0.1/(a^2+0.01)
    float a = he + EPSF;
    float den = a * a + 0.01f;
    float lin = (a * gW[0] + 0.1f * gW[1]) / den + gb[0];  // GATE_SCALE = 1
    float g = 1.f / (1.f + expf(-lin));

    // row sum + normalize: out = aw * g / (g*rowsum + EPS)
    float acc = 0.f;
#pragma unroll
    for (int k = 0; k < 4; ++k)
        acc += v[k].x + v[k].y + v[k].z + v[k].w;
#pragma unroll
    for (int off = 1; off < 64; off <<= 1) acc += __shfl_xor(acc, off);
    float scale = g / (g * acc + EPSF);
    fx4* o = (fx4*)(out + rowbase);
#pragma unroll
    for (int k = 0; k < 4; ++k) {
        fx4 wv = v[k] * scale;
        __builtin_nontemporal_store(wv, o + lane + k * 64);
    }
}

extern "C" void kernel_launch(void* const* d_in, const int* in_sizes, int n_in,
                              void* d_out, int out_size, void* d_ws, size_t ws_size,
                              hipStream_t stream) {
    const float* x  = (const float*)d_in[0];
    const float* aw = (const float*)d_in[1];
    const float* Wd = (const float*)d_in[2];
    const float* bd = (const float*)d_in[3];
    const float* gW = (const float*)d_in[8];
    const float* gb = (const float*)d_in[9];
    float* out = (float*)d_out;
    float* ws = (float*)d_ws;  // [0,2048) wsum; [2048] sum(bd)

    (void)hipMemsetAsync(ws, 0, (DD + 1) * sizeof(float), stream);
    k_colsum<<<256, 256, 0, stream>>>(Wd, bd, ws);
    k_norm<<<BB * HH * SS / 4, 256, 0, stream>>>(aw, x, ws, gW, gb, out);
}